// Round 1
// baseline (305.726 us; speedup 1.0000x reference)
//
#include <hip/hip_runtime.h>

#define NB 4096   // batch
#define NT 512    // time steps
#define ND 32     // input features
#define NH 16     // hidden

__device__ __forceinline__ float sigm(float y) {
    return __builtin_amdgcn_rcpf(1.0f + __expf(-y));
}
__device__ __forceinline__ float tanh_fast(float y) {
    // tanh(y) = 1 - 2/(1+e^{2y}); saturates correctly at +/-1
    return fmaf(-2.0f, __builtin_amdgcn_rcpf(1.0f + __expf(2.0f * y)), 1.0f);
}
__device__ __forceinline__ float bcast_lane(float v, int srcLane) {
    return __int_as_float(__builtin_amdgcn_readlane(__float_as_int(v), srcLane));
}

// One wave per batch element. Lane j computes gate column j of z (4H=64).
// Gates packed [i | f | g | o] along lanes: i=0..15, f=16..31, g=32..47, o=48..63.
__global__ __launch_bounds__(256, 4) void lstm_wave_kernel(
    const float* __restrict__ x,   // (B, T, D)
    const float* __restrict__ Wx,  // (D, 4H)
    const float* __restrict__ Wh,  // (H, 4H)
    const float* __restrict__ bh,  // (4H)
    const float* __restrict__ Wd,  // (H, 2)
    const float* __restrict__ bd,  // (2)
    float* __restrict__ out)       // (B, 2)
{
    __shared__ float lds[4][2][256];  // [wave][dbuf][8 steps * 32 feats]

    const int lane = threadIdx.x & 63;
    const int wv = threadIdx.x >> 6;
    const int b = (blockIdx.x << 2) + wv;

    // Per-lane weight columns, resident in registers for the whole sequence.
    float wx[ND];
#pragma unroll
    for (int k = 0; k < ND; ++k) wx[k] = Wx[k * 64 + lane];
    float wh[NH];
#pragma unroll
    for (int k = 0; k < NH; ++k) wh[k] = Wh[k * 64 + lane];
    const float bias = bh[lane];

    // Branchless activation constants: a = sigm(z*sA)*sM + sB
    // (tanh(z) = 2*sigm(2z) - 1 for the g lanes 32..47)
    const bool is_g = (lane >= 32) && (lane < 48);
    const float sA = is_g ? 2.0f : 1.0f;
    const float sM = is_g ? 2.0f : 1.0f;
    const float sB = is_g ? -1.0f : 0.0f;

    const float4* __restrict__ xb4 = (const float4*)(x + (size_t)b * NT * ND);
    float4* buf0 = (float4*)&lds[wv][0][0];
    float4* buf1 = (float4*)&lds[wv][1][0];

    // Prologue: stage chunk 0 (8 timesteps = 256 floats = 64 lanes * float4).
    float4 cur = xb4[lane];
    buf0[lane] = cur;

    float c = 0.0f, h = 0.0f;

    for (int tc = 0; tc < NT / 8; ++tc) {
        // Prefetch next chunk from global while computing this one.
        float4 nxt;
        const bool have_next = (tc + 1 < NT / 8);
        if (have_next) nxt = xb4[(tc + 1) * 64 + lane];

        const float* src = &lds[wv][tc & 1][0];
#pragma unroll
        for (int s = 0; s < 8; ++s) {
            float z = bias;
            // x contribution: uniform-address LDS reads (broadcast), per-lane weights.
#pragma unroll
            for (int k = 0; k < ND; ++k)
                z = fmaf(src[s * 32 + k], wx[k], z);
            // h contribution: broadcast h[k] from lane k via readlane.
#pragma unroll
            for (int k = 0; k < NH; ++k)
                z = fmaf(bcast_lane(h, k), wh[k], z);

            // Activation (branchless select between sigmoid and tanh).
            float a = fmaf(sigm(z * sA), sM, sB);

            // Gather f, g, o into lanes 0..15 (i is this lane's own a).
            float af = __shfl_xor(a, 16);
            float ag = __shfl_xor(a, 32);
            float ao = __shfl_xor(a, 48);

            float cn = fmaf(af, c, a * ag);  // c_new = f*c + i*g
            c = cn;
            h = ao * tanh_fast(cn);          // h_new = o * tanh(c_new)
        }

        if (have_next) {
            float4* dst = (((tc + 1) & 1) ? buf1 : buf0);
            dst[lane] = nxt;
        }
    }

    // logits = c_fin @ Wd + bd  (cell state!), then softmax over 2.
    float l0 = bd[0], l1 = bd[1];
#pragma unroll
    for (int k = 0; k < NH; ++k) {
        float ck = bcast_lane(c, k);
        l0 = fmaf(ck, Wd[k * 2 + 0], l0);
        l1 = fmaf(ck, Wd[k * 2 + 1], l1);
    }
    if (lane == 0) {
        out[b * 2 + 0] = sigm(l0 - l1);  // softmax_0 = 1/(1+e^{l1-l0})
        out[b * 2 + 1] = sigm(l1 - l0);
    }
}

extern "C" void kernel_launch(void* const* d_in, const int* in_sizes, int n_in,
                              void* d_out, int out_size, void* d_ws, size_t ws_size,
                              hipStream_t stream) {
    const float* x  = (const float*)d_in[0];
    const float* Wx = (const float*)d_in[1];
    const float* Wh = (const float*)d_in[2];
    const float* bh = (const float*)d_in[3];
    const float* Wd = (const float*)d_in[4];
    const float* bd = (const float*)d_in[5];
    float* out = (float*)d_out;

    dim3 grid(NB / 4);
    dim3 block(256);
    hipLaunchKernelGGL(lstm_wave_kernel, grid, block, 0, stream,
                       x, Wx, Wh, bh, Wd, bd, out);
}

// Round 2
// 287.980 us; speedup vs baseline: 1.0616x; 1.0616x over previous
//
#include <hip/hip_runtime.h>

#define NB 4096   // batch
#define NT 512    // time steps
#define ND 32     // input features
#define NH 16     // hidden

typedef float f32x2 __attribute__((ext_vector_type(2)));
typedef float f32x4 __attribute__((ext_vector_type(4)));

// Packed fp32 FMA: acc.x += a.x*b.x; acc.y += a.y*b.y  (one VALU instr)
__device__ __forceinline__ void pk_fma(f32x2& acc, f32x2 a, f32x2 b) {
    asm("v_pk_fma_f32 %0, %1, %2, %0" : "+v"(acc) : "v"(a), "v"(b));
}

__device__ __forceinline__ float bcast_lane(float v, int srcLane) {
    return __int_as_float(__builtin_amdgcn_readlane(__float_as_int(v), srcLane));
}

// One wave per batch element. Lane j computes gate column j of z (4H=64).
// Gates packed [i | f | g | o] along lanes: i=0..15, f=16..31, g=32..47, o=48..63.
__global__ __launch_bounds__(256, 4) void lstm_wave_kernel(
    const float* __restrict__ x,   // (B, T, D)
    const float* __restrict__ Wx,  // (D, 4H)
    const float* __restrict__ Wh,  // (H, 4H)
    const float* __restrict__ bh,  // (4H)
    const float* __restrict__ Wd,  // (H, 2)
    const float* __restrict__ bd,  // (2)
    float* __restrict__ out)       // (B, 2)
{
    __shared__ float ldsx[4][2][256];  // [wave][dbuf][8 steps * 32 feats]
    __shared__ float hbuf[4][64];      // [wave][h broadcast buffer]

    const int lane = threadIdx.x & 63;
    const int wv = threadIdx.x >> 6;
    const int b = (blockIdx.x << 2) + wv;

    // Per-lane weight columns as packed pairs over k (resident in registers).
    f32x2 wx2[16];
#pragma unroll
    for (int q = 0; q < 16; ++q)
        wx2[q] = f32x2{Wx[(2 * q) * 64 + lane], Wx[(2 * q + 1) * 64 + lane]};
    f32x2 wh2[8];
#pragma unroll
    for (int q = 0; q < 8; ++q)
        wh2[q] = f32x2{Wh[(2 * q) * 64 + lane], Wh[(2 * q + 1) * 64 + lane]};
    const float bias = bh[lane];

    // Branchless activation constants: a = sM * sigm(-nA*z) + sB
    // (tanh(z) = 2*sigm(2z) - 1 for the g lanes 32..47)
    const bool is_g = (lane >= 32) && (lane < 48);
    const float nA = is_g ? -2.0f : -1.0f;
    const float sM = is_g ? 2.0f : 1.0f;
    const float sB = is_g ? -1.0f : 0.0f;

    // Loop-invariant bpermute byte addresses for the gate gathers.
    const int a16 = (lane ^ 16) << 2;
    const int a32 = (lane ^ 32) << 2;
    const int a48 = (lane ^ 48) << 2;

    const f32x4* __restrict__ xb4 = (const f32x4*)(x + (size_t)b * NT * ND);

    // Prologue: stage chunk 0 (8 timesteps = 256 floats = 64 lanes * float4),
    // zero the h broadcast buffer (same-wave producer/consumer, no barrier).
    ((f32x4*)&ldsx[wv][0][0])[lane] = xb4[lane];
    hbuf[wv][lane] = 0.0f;

    const f32x4* hb4 = (const f32x4*)&hbuf[wv][0];

    float c = 0.0f;

    for (int tc = 0; tc < NT / 8; ++tc) {
        // Prefetch next chunk from global while computing this one.
        f32x4 nxt;
        const bool have_next = (tc + 1 < NT / 8);
        if (have_next) nxt = xb4[(tc + 1) * 64 + lane];

        const f32x4* s4 = (const f32x4*)&ldsx[wv][tc & 1][0];
#pragma unroll
        for (int s = 0; s < 8; ++s) {
            f32x2 zA = f32x2{bias, 0.0f};
            f32x2 zB = f32x2{0.0f, 0.0f};

            // h contribution: uniform-address LDS broadcast of h (written at
            // the end of the previous step by lanes 0..15 of this wave).
            f32x4 hv0 = hb4[0], hv1 = hb4[1], hv2 = hb4[2], hv3 = hb4[3];
            pk_fma(zA, f32x2{hv0.x, hv0.y}, wh2[0]);
            pk_fma(zB, f32x2{hv0.z, hv0.w}, wh2[1]);
            pk_fma(zA, f32x2{hv1.x, hv1.y}, wh2[2]);
            pk_fma(zB, f32x2{hv1.z, hv1.w}, wh2[3]);
            pk_fma(zA, f32x2{hv2.x, hv2.y}, wh2[4]);
            pk_fma(zB, f32x2{hv2.z, hv2.w}, wh2[5]);
            pk_fma(zA, f32x2{hv3.x, hv3.y}, wh2[6]);
            pk_fma(zB, f32x2{hv3.z, hv3.w}, wh2[7]);

            // x contribution: uniform-address LDS b128 broadcasts + packed FMA.
#pragma unroll
            for (int q = 0; q < 8; ++q) {
                f32x4 v = s4[s * 8 + q];
                pk_fma(zA, f32x2{v.x, v.y}, wx2[2 * q]);
                pk_fma(zB, f32x2{v.z, v.w}, wx2[2 * q + 1]);
            }
            f32x2 zs = zA + zB;
            float z = zs.x + zs.y;

            // Activation (branchless select between sigmoid and tanh).
            float e = __expf(nA * z);
            float a = fmaf(sM, __builtin_amdgcn_rcpf(1.0f + e), sB);

            // Gather f, g, o into lanes 0..15 (i is this lane's own a).
            float af = __int_as_float(__builtin_amdgcn_ds_bpermute(a16, __float_as_int(a)));
            float ag = __int_as_float(__builtin_amdgcn_ds_bpermute(a32, __float_as_int(a)));
            float ao = __int_as_float(__builtin_amdgcn_ds_bpermute(a48, __float_as_int(a)));

            float cn = fmaf(af, c, a * ag);  // c_new = f*c + i*g
            c = cn;
            // tanh(cn) = 1 - 2/(1+e^{2cn}); saturates correctly at +/-1
            float et = __expf(2.0f * cn);
            float t = fmaf(-2.0f, __builtin_amdgcn_rcpf(1.0f + et), 1.0f);
            float h = ao * t;                // h_new = o * tanh(c_new)
            hbuf[wv][lane] = h;              // lanes 0..15 hold the true h
        }

        if (have_next)
            ((f32x4*)&ldsx[wv][(tc + 1) & 1][0])[lane] = nxt;
    }

    // logits = c_fin @ Wd + bd  (cell state!), then softmax over 2.
    float l0 = bd[0], l1 = bd[1];
#pragma unroll
    for (int k = 0; k < NH; ++k) {
        float ck = bcast_lane(c, k);
        l0 = fmaf(ck, Wd[k * 2 + 0], l0);
        l1 = fmaf(ck, Wd[k * 2 + 1], l1);
    }
    if (lane == 0) {
        float e01 = __expf(l1 - l0);
        float e10 = __expf(l0 - l1);
        out[b * 2 + 0] = __builtin_amdgcn_rcpf(1.0f + e01);  // softmax_0
        out[b * 2 + 1] = __builtin_amdgcn_rcpf(1.0f + e10);  // softmax_1
    }
}

extern "C" void kernel_launch(void* const* d_in, const int* in_sizes, int n_in,
                              void* d_out, int out_size, void* d_ws, size_t ws_size,
                              hipStream_t stream) {
    const float* x  = (const float*)d_in[0];
    const float* Wx = (const float*)d_in[1];
    const float* Wh = (const float*)d_in[2];
    const float* bh = (const float*)d_in[3];
    const float* Wd = (const float*)d_in[4];
    const float* bd = (const float*)d_in[5];
    float* out = (float*)d_out;

    dim3 grid(NB / 4);
    dim3 block(256);
    hipLaunchKernelGGL(lstm_wave_kernel, grid, block, 0, stream,
                       x, Wx, Wh, bh, Wd, bd, out);
}

// Round 3
// 217.120 us; speedup vs baseline: 1.4081x; 1.3264x over previous
//
#include <hip/hip_runtime.h>

#define NB 4096   // batch
#define NT 512    // time steps
#define ND 32     // input features
#define NH 16     // hidden
#define CH 16     // timesteps per MFMA chunk
#define NCH (NT/CH)

typedef float f32x4 __attribute__((ext_vector_type(4)));
typedef short short8 __attribute__((ext_vector_type(8)));
typedef unsigned int uint4v __attribute__((ext_vector_type(4)));

__device__ __forceinline__ unsigned cvt_pk_bf16(float lo, float hi) {
    unsigned r;
    asm("v_cvt_pk_bf16_f32 %0, %1, %2" : "=v"(r) : "v"(lo), "v"(hi));
    return r;
}
__device__ __forceinline__ float bcast_lane(float v, int srcLane) {
    return __int_as_float(__builtin_amdgcn_readlane(__float_as_int(v), srcLane));
}

// One wave per batch element. Gate-lane space: lane j = gate column j of the
// packed [i|f|g|o] 64-gate vector (i=0..15, f=16..31, g=32..47, o=48..63).
// z_x = x@Wx computed 16 steps at a time with mfma_f32_16x16x32_bf16 (K=32=D);
// recurrence (h@Wh, activations, c/h update) stays exact fp32 on the VALU.
__global__ __launch_bounds__(256, 4) void lstm_mfma_kernel(
    const float* __restrict__ x,   // (B, T, D)
    const float* __restrict__ Wx,  // (D, 4H)
    const float* __restrict__ Wh,  // (H, 4H)
    const float* __restrict__ bh,  // (4H)
    const float* __restrict__ Wd,  // (H, 2)
    const float* __restrict__ bd,  // (2)
    float* __restrict__ out)       // (B, 2)
{
    __shared__ float zxb[4][64][17];  // [wave][gate][step] pad 17 -> conflict-free reads

    const int lane = threadIdx.x & 63;
    const int wv = threadIdx.x >> 6;
    const int b = (blockIdx.x << 2) + wv;

    const int coln = lane & 15;   // A: M-row (step-in-chunk); B: N-col within tile
    const int kgrp = lane >> 4;   // K-group
    const int k0 = kgrp * 8;      // this lane's K base (8 contiguous k)

    // B-frags: Wx columns n*16+coln, k=k0..k0+7, converted to bf16 once.
    short8 bfrag[4];
#pragma unroll
    for (int n = 0; n < 4; ++n) {
        uint4v u;
#pragma unroll
        for (int q = 0; q < 4; ++q) {
            float f0 = Wx[(k0 + 2 * q) * 64 + n * 16 + coln];
            float f1 = Wx[(k0 + 2 * q + 1) * 64 + n * 16 + coln];
            u[q] = cvt_pk_bf16(f0, f1);
        }
        bfrag[n] = __builtin_bit_cast(short8, u);
    }
    float biasn[4];
#pragma unroll
    for (int n = 0; n < 4; ++n) biasn[n] = bh[n * 16 + coln];

    // Per-lane Wh column (fp32, register-resident).
    float wh[NH];
#pragma unroll
    for (int k = 0; k < NH; ++k) wh[k] = Wh[k * 64 + lane];

    // Branchless activation constants: a = sM * sigm-core + sB
    const bool is_g = (lane >= 32) && (lane < 48);
    const float nA = is_g ? -2.0f : -1.0f;
    const float sM = is_g ? 2.0f : 1.0f;
    const float sB = is_g ? -1.0f : 0.0f;

    // Loop-invariant bpermute byte addresses for the gate gathers.
    const int a16 = (lane ^ 16) << 2;
    const int a32 = (lane ^ 32) << 2;
    const int a48 = (lane ^ 48) << 2;

    // A-frag source: step row = coln (within chunk), feats k0..k0+7 (32B).
    const float* xrow = x + (size_t)b * NT * ND + coln * ND + k0;

    f32x4 xa0 = *(const f32x4*)(xrow);
    f32x4 xa1 = *(const f32x4*)(xrow + 4);

    float c = 0.0f, h = 0.0f;
    float* zrow = &zxb[wv][lane][0];  // this lane's gate row

    for (int tc = 0; tc < NCH; ++tc) {
        // Prefetch next chunk's A-frag source from global (latency hidden
        // under the 16 serial recurrence steps below).
        f32x4 xn0, xn1;
        const bool have_next = (tc + 1 < NCH);
        if (have_next) {
            xn0 = *(const f32x4*)(xrow + (tc + 1) * CH * ND);
            xn1 = *(const f32x4*)(xrow + (tc + 1) * CH * ND + 4);
        }

        // Convert current chunk to bf16 A-frag.
        uint4v ua;
        ua[0] = cvt_pk_bf16(xa0.x, xa0.y);
        ua[1] = cvt_pk_bf16(xa0.z, xa0.w);
        ua[2] = cvt_pk_bf16(xa1.x, xa1.y);
        ua[3] = cvt_pk_bf16(xa1.z, xa1.w);
        short8 afrag = __builtin_bit_cast(short8, ua);

        // z_x for 16 steps x 64 gates: 4 MFMAs (N-tiles of 16), bias in C-init.
        // C layout: col = lane&15 (gate within tile), row = kgrp*4+r (step).
#pragma unroll
        for (int n = 0; n < 4; ++n) {
            f32x4 acc = {biasn[n], biasn[n], biasn[n], biasn[n]};
            acc = __builtin_amdgcn_mfma_f32_16x16x32_bf16(afrag, bfrag[n], acc, 0, 0, 0);
#pragma unroll
            for (int r = 0; r < 4; ++r)
                zxb[wv][n * 16 + coln][kgrp * 4 + r] = acc[r];
        }

        // Serial recurrence over the chunk (fp32 exact).
#pragma unroll
        for (int s = 0; s < CH; ++s) {
            float z0 = zrow[s], z1 = 0.0f;  // per-lane ds_read_b32, stride 17: conflict-free
#pragma unroll
            for (int k = 0; k < NH; k += 2) {
                z0 = fmaf(bcast_lane(h, k),     wh[k],     z0);
                z1 = fmaf(bcast_lane(h, k + 1), wh[k + 1], z1);
            }
            float z = z0 + z1;

            float e = __expf(nA * z);
            float a = fmaf(sM, __builtin_amdgcn_rcpf(1.0f + e), sB);

            float af = __int_as_float(__builtin_amdgcn_ds_bpermute(a16, __float_as_int(a)));
            float ag = __int_as_float(__builtin_amdgcn_ds_bpermute(a32, __float_as_int(a)));
            float ao = __int_as_float(__builtin_amdgcn_ds_bpermute(a48, __float_as_int(a)));

            float cn = fmaf(af, c, a * ag);  // lanes 0..15: c_new = f*c + i*g
            c = cn;
            float et = __expf(2.0f * cn);    // tanh(cn) = 1 - 2/(1+e^{2cn})
            float t = fmaf(-2.0f, __builtin_amdgcn_rcpf(1.0f + et), 1.0f);
            h = ao * t;                      // lanes 0..15 hold the true h
        }

        xa0 = xn0; xa1 = xn1;
    }

    // logits = c_fin @ Wd + bd  (cell state!), then softmax over 2.
    float l0 = bd[0], l1 = bd[1];
#pragma unroll
    for (int k = 0; k < NH; ++k) {
        float ck = bcast_lane(c, k);
        l0 = fmaf(ck, Wd[k * 2 + 0], l0);
        l1 = fmaf(ck, Wd[k * 2 + 1], l1);
    }
    if (lane == 0) {
        float e01 = __expf(l1 - l0);
        float e10 = __expf(l0 - l1);
        out[b * 2 + 0] = __builtin_amdgcn_rcpf(1.0f + e01);
        out[b * 2 + 1] = __builtin_amdgcn_rcpf(1.0f + e10);
    }
}

extern "C" void kernel_launch(void* const* d_in, const int* in_sizes, int n_in,
                              void* d_out, int out_size, void* d_ws, size_t ws_size,
                              hipStream_t stream) {
    const float* x  = (const float*)d_in[0];
    const float* Wx = (const float*)d_in[1];
    const float* Wh = (const float*)d_in[2];
    const float* bh = (const float*)d_in[3];
    const float* Wd = (const float*)d_in[4];
    const float* bd = (const float*)d_in[5];
    float* out = (float*)d_out;

    dim3 grid(NB / 4);
    dim3 block(256);
    hipLaunchKernelGGL(lstm_mfma_kernel, grid, block, 0, stream,
                       x, Wx, Wh, bh, Wd, bd, out);
}

// Round 4
// 133.761 us; speedup vs baseline: 2.2856x; 1.6232x over previous
//
#include <hip/hip_runtime.h>

#define NB 4096   // batch
#define NT 512    // time steps
#define ND 32     // input features
#define NH 16     // hidden
#define CH 16     // timesteps per MFMA chunk
#define NCH (NT/CH)

typedef float f32x2 __attribute__((ext_vector_type(2)));
typedef float f32x4 __attribute__((ext_vector_type(4)));
typedef short short8 __attribute__((ext_vector_type(8)));
typedef unsigned int uint4v __attribute__((ext_vector_type(4)));

__device__ __forceinline__ unsigned cvt_pk_bf16(float lo, float hi) {
    unsigned r;
    asm("v_cvt_pk_bf16_f32 %0, %1, %2" : "=v"(r) : "v"(lo), "v"(hi));
    return r;
}
// Packed fp32 FMA: acc.x += a.x*b.x; acc.y += a.y*b.y (one VALU instr)
__device__ __forceinline__ void pk_fma(f32x2& acc, f32x2 a, f32x2 b) {
    asm("v_pk_fma_f32 %0, %1, %2, %0" : "+v"(acc) : "v"(a), "v"(b));
}
__device__ __forceinline__ float sigm(float y) {
    return __builtin_amdgcn_rcpf(1.0f + __expf(-y));
}
__device__ __forceinline__ float tanh_fast(float y) {
    return fmaf(-2.0f, __builtin_amdgcn_rcpf(1.0f + __expf(2.0f * y)), 1.0f);
}

// 4 batches per wave. Lane = (p = lane>>4: batch-in-wave, u = lane&15: hidden
// unit). Each lane computes gates i,f,g,o of unit u for batch p -> c/h update
// is fully lane-local (no gather). z_x = x@Wx via MFMA per 16-step chunk
// (R3-verified fragment layouts); recurrence stays exact fp32.
__global__ __launch_bounds__(256, 1) void lstm4_kernel(
    const float* __restrict__ x,   // (B, T, D)
    const float* __restrict__ Wx,  // (D, 4H) cols packed [i|f|g|o]
    const float* __restrict__ Wh,  // (H, 4H)
    const float* __restrict__ bh,  // (4H)
    const float* __restrict__ Wd,  // (H, 2)
    const float* __restrict__ bd,  // (2)
    float* __restrict__ out)       // (B, 2)
{
    __shared__ float zxb[4][4][CH][NH][4];  // [wave][p][step][u][i,f,g,o] = 64 KB
    __shared__ float hbuf[4][4][NH];        // [wave][p][u]

    const int lane = threadIdx.x & 63;
    const int wv = threadIdx.x >> 6;
    const int u = lane & 15;    // hidden unit (recurrence) / row,col (MFMA)
    const int p = lane >> 4;    // batch-in-wave (recurrence) / K-group (MFMA)
    const int k0 = p * 8;

    const int b0 = (blockIdx.x * 4 + wv) * 4;

    // MFMA B-frags: Wx cols n*16+u, k=k0..k0+7 (bf16). Verified layout (R3).
    short8 bfrag[4];
    float biasn[4];
#pragma unroll
    for (int n = 0; n < 4; ++n) {
        uint4v w;
#pragma unroll
        for (int q = 0; q < 4; ++q)
            w[q] = cvt_pk_bf16(Wx[(k0 + 2 * q) * 64 + n * 16 + u],
                               Wx[(k0 + 2 * q + 1) * 64 + n * 16 + u]);
        bfrag[n] = __builtin_bit_cast(short8, w);
        biasn[n] = bh[n * 16 + u];
    }

    // Wh columns for this lane's 4 gates, packed over k-pairs (fp32 exact).
    f32x2 wh_i[8], wh_f[8], wh_g[8], wh_o[8];
#pragma unroll
    for (int j = 0; j < 8; ++j) {
        wh_i[j] = f32x2{Wh[(2 * j) * 64 + u],      Wh[(2 * j + 1) * 64 + u]};
        wh_f[j] = f32x2{Wh[(2 * j) * 64 + 16 + u], Wh[(2 * j + 1) * 64 + 16 + u]};
        wh_g[j] = f32x2{Wh[(2 * j) * 64 + 32 + u], Wh[(2 * j + 1) * 64 + 32 + u]};
        wh_o[j] = f32x2{Wh[(2 * j) * 64 + 48 + u], Wh[(2 * j + 1) * 64 + 48 + u]};
    }

    // x A-frag sources: for batch q, this lane supplies row (step) = u,
    // feats k0..k0+7. (Identical per-lane pattern to R3, which passed.)
    const float* xb[4];
#pragma unroll
    for (int q = 0; q < 4; ++q)
        xb[q] = x + ((size_t)(b0 + q) * NT + u) * ND + k0;

    f32x4 xa[4][2], xn[4][2];
#pragma unroll
    for (int q = 0; q < 4; ++q) {
        xa[q][0] = *(const f32x4*)(xb[q]);
        xa[q][1] = *(const f32x4*)(xb[q] + 4);
    }

    hbuf[wv][p][u] = 0.0f;
    float c = 0.0f;

    for (int tc = 0; tc < NCH; ++tc) {
        const bool have_next = (tc + 1 < NCH);
        if (have_next) {
#pragma unroll
            for (int q = 0; q < 4; ++q) {
                xn[q][0] = *(const f32x4*)(xb[q] + (tc + 1) * CH * ND);
                xn[q][1] = *(const f32x4*)(xb[q] + (tc + 1) * CH * ND + 4);
            }
        }

        // z_x for 4 batches x 16 steps x 64 gates: 16 MFMAs, bias in C-init.
#pragma unroll
        for (int q = 0; q < 4; ++q) {
            uint4v ua;
            ua[0] = cvt_pk_bf16(xa[q][0].x, xa[q][0].y);
            ua[1] = cvt_pk_bf16(xa[q][0].z, xa[q][0].w);
            ua[2] = cvt_pk_bf16(xa[q][1].x, xa[q][1].y);
            ua[3] = cvt_pk_bf16(xa[q][1].z, xa[q][1].w);
            short8 afrag = __builtin_bit_cast(short8, ua);
            f32x4 acc[4];
#pragma unroll
            for (int n = 0; n < 4; ++n) {
                acc[n] = f32x4{biasn[n], biasn[n], biasn[n], biasn[n]};
                acc[n] = __builtin_amdgcn_mfma_f32_16x16x32_bf16(afrag, bfrag[n], acc[n], 0, 0, 0);
            }
            // C: col(lane&15)=gate-u, row((lane>>4)*4+r)=step. Regroup the 4
            // gate-quarters into one f32x4 -> single ds_write_b128 per r.
#pragma unroll
            for (int r = 0; r < 4; ++r) {
                f32x4 v = f32x4{acc[0][r], acc[1][r], acc[2][r], acc[3][r]};
                *(f32x4*)&zxb[wv][q][p * 4 + r][u][0] = v;
            }
        }

        // Serial recurrence over the chunk (fp32 exact, all 64 lanes useful).
#pragma unroll
        for (int s = 0; s < CH; ++s) {
            f32x4 zx = *(const f32x4*)&zxb[wv][p][s][u][0];  // (zi,zf,zg,zo)
            f32x4 h0 = *(const f32x4*)&hbuf[wv][p][0];
            f32x4 h1 = *(const f32x4*)&hbuf[wv][p][4];
            f32x4 h2 = *(const f32x4*)&hbuf[wv][p][8];
            f32x4 h3 = *(const f32x4*)&hbuf[wv][p][12];

            f32x2 zi = f32x2{zx.x, 0.0f}, zf = f32x2{zx.y, 0.0f};
            f32x2 zg = f32x2{zx.z, 0.0f}, zo = f32x2{zx.w, 0.0f};
            f32x2 hp;
#define HSTEP(J, HV, A, B)                                            \
            hp = f32x2{HV.A, HV.B};                                   \
            pk_fma(zi, hp, wh_i[J]); pk_fma(zf, hp, wh_f[J]);         \
            pk_fma(zg, hp, wh_g[J]); pk_fma(zo, hp, wh_o[J]);
            HSTEP(0, h0, x, y) HSTEP(1, h0, z, w)
            HSTEP(2, h1, x, y) HSTEP(3, h1, z, w)
            HSTEP(4, h2, x, y) HSTEP(5, h2, z, w)
            HSTEP(6, h3, x, y) HSTEP(7, h3, z, w)
#undef HSTEP
            float ai = sigm(zi.x + zi.y);
            float af = sigm(zf.x + zf.y);
            float ag = tanh_fast(zg.x + zg.y);
            float ao = sigm(zo.x + zo.y);

            float cn = fmaf(af, c, ai * ag);   // lane-local: no gather needed
            c = cn;
            float h = ao * tanh_fast(cn);
            hbuf[wv][p][u] = h;
        }

#pragma unroll
        for (int q = 0; q < 4; ++q) {
            if (have_next) { xa[q][0] = xn[q][0]; xa[q][1] = xn[q][1]; }
        }
    }

    // logits[p] = c[p,:] @ Wd + bd; reduce over u within each 16-lane group.
    f32x2 wd = *(const f32x2*)&Wd[u * 2];
    float l0 = c * wd.x;
    float l1 = c * wd.y;
#pragma unroll
    for (int m = 1; m < 16; m <<= 1) {
        l0 += __shfl_xor(l0, m);
        l1 += __shfl_xor(l1, m);
    }
    if (u == 0) {
        l0 += bd[0];
        l1 += bd[1];
        float s0 = sigm(l0 - l1);
        float s1 = sigm(l1 - l0);
        *(f32x2*)&out[(b0 + p) * 2] = f32x2{s0, s1};
    }
}

extern "C" void kernel_launch(void* const* d_in, const int* in_sizes, int n_in,
                              void* d_out, int out_size, void* d_ws, size_t ws_size,
                              hipStream_t stream) {
    const float* x  = (const float*)d_in[0];
    const float* Wx = (const float*)d_in[1];
    const float* Wh = (const float*)d_in[2];
    const float* bh = (const float*)d_in[3];
    const float* Wd = (const float*)d_in[4];
    const float* bd = (const float*)d_in[5];
    float* out = (float*)d_out;

    dim3 grid(NB / 16);   // 4 waves/block x 4 batches/wave
    dim3 block(256);
    hipLaunchKernelGGL(lstm4_kernel, grid, block, 0, stream,
                       x, Wx, Wh, bh, Wd, bd, out);
}